// Round 9
// baseline (445.462 us; speedup 1.0000x reference)
//
#include <hip/hip_runtime.h>
#include <stdint.h>

#define TPB 1024
#define NL 4
#define XS 33      // u32 row stride (+1 pad keeps row/col LDS access ~conflict-free)
#define HWS 17     // per-row u32 stride of per-wave H slice (odd -> bank spread)

typedef _Float16 f16;
typedef _Float16 half2v __attribute__((ext_vector_type(2)));
typedef _Float16 f16x8 __attribute__((ext_vector_type(8)));
typedef float f32x4 __attribute__((ext_vector_type(4)));
typedef uint32_t u32x4 __attribute__((ext_vector_type(4)));

static __device__ __forceinline__ uint32_t packh2(float a, float b) {
  half2v h;
  h.x = (_Float16)a;
  h.y = (_Float16)b;
  return __builtin_bit_cast(uint32_t, h);
}
static __device__ __forceinline__ float2 unpackh2(uint32_t u) {
  half2v h = __builtin_bit_cast(half2v, u);
  return make_float2((float)h.x, (float)h.y);
}

// w1h/w2h: plain f16 copies of ff1_w/ff2_w in [l][o][d] layout (A-fragment =
// one aligned 16B load). petab[s][d] = PE(s,d) when petab != nullptr.
__global__ void pack_weights_kernel(const float* __restrict__ ff1_w,
                                    const float* __restrict__ ff2_w,
                                    f16* __restrict__ w1h,
                                    f16* __restrict__ w2h,
                                    float* __restrict__ petab) {
  int idx = blockIdx.x * blockDim.x + threadIdx.x;
  if (idx < 16384) {
    w1h[idx] = (f16)ff1_w[idx];
  } else if (idx < 32768) {
    w2h[idx - 16384] = (f16)ff2_w[idx - 16384];
  } else if (petab != nullptr && idx < 32768 + 64000) {
    int j = idx - 32768;
    int s = j >> 6, d = j & 63;
    float div = exp2f(-0.4152410118609203f * (float)(d >> 1));
    float ang = (float)s * div;
    petab[j] = (d & 1) ? cosf(ang) : sinf(ang);
  }
}

// Wave-independent FF via swapped MFMA (R8 post-mortem):
//   H^T = mfma(A=W1, B=Y^T), T^T = mfma(A=W2, B=H) -- B-col = seq-row, so
// each wave owns 64 rows end-to-end: mm1 -> per-wave H slice (no barrier,
// wave-internal lgkmcnt ordering) -> mm2 -> in-register LN2 (lane holds 16
// T-values of one row; row-reduce = shfl_xor 16,32). All LDS traffic is
// u32-granular (R8's u16 scatters caused 2.9e7 bank conflicts). Barriers:
// 21/layer -> 3/layer. Fragment mappings as verified by R8's pass:
// A/B: lane&15=row/col, k=8*(lane>>4)+j; C/D: col=lane&15, row=4*(lane>>4)+i.
__global__ __launch_bounds__(TPB) void aat_kernel(
    const int* __restrict__ tokens, const float* __restrict__ emb,
    const float* __restrict__ lin_w, const float* __restrict__ lin_b,
    const float* __restrict__ ff1_b, const float* __restrict__ ff2_b,
    const float* __restrict__ n1_g, const float* __restrict__ n1_b,
    const float* __restrict__ n2_g, const float* __restrict__ n2_b,
    const float* __restrict__ out_w, const float* __restrict__ out_b,
    const f16* __restrict__ w1h, const f16* __restrict__ w2h,
    const float* __restrict__ petab, float* __restrict__ out) {
  __shared__ uint32_t X[1024 * XS];       // 135168 B: rows as f16 pairs
  __shared__ uint32_t scratch[16 * 16 * HWS];  // 17408 B: avg redbuf / per-wave H
  __shared__ float avgbuf[64];
  __shared__ __align__(8) float attnbuf[64];

  const int t = threadIdx.x;
  const int b = blockIdx.x;
  const int lane = t & 63;
  const int wv = t >> 6;                  // 0..15
  const bool valid = (t < 1000);
  const int base = t * XS;
  float* redbuf = (float*)scratch;        // [32][64] f32 during avg phase

  // ---------------- embed * sqrt(d) + positional encoding -> X ----------------
  if (valid) {
    int tok = tokens[b * 1000 + t];
    const float4* ev = (const float4*)(emb + (size_t)tok * 64);
    if (petab != nullptr) {
      const float4* pv = (const float4*)(petab + (size_t)t * 64);
      #pragma unroll
      for (int q = 0; q < 16; q++) {
        float4 v4 = ev[q];
        float4 p4 = pv[q];
        X[base + 2 * q] = packh2(fmaf(v4.x, 8.f, p4.x), fmaf(v4.y, 8.f, p4.y));
        X[base + 2 * q + 1] = packh2(fmaf(v4.z, 8.f, p4.z), fmaf(v4.w, 8.f, p4.w));
      }
    } else {
      float fs = (float)t;
      #pragma unroll
      for (int q = 0; q < 16; q++) {
        float4 v4 = ev[q];
        float d0 = exp2f(-0.4152410118609203f * (float)((4 * q) >> 1));
        float d1 = exp2f(-0.4152410118609203f * (float)((4 * q + 2) >> 1));
        float pe0 = sinf(fs * d0), pe1 = cosf(fs * d0);
        float pe2 = sinf(fs * d1), pe3 = cosf(fs * d1);
        X[base + 2 * q] = packh2(fmaf(v4.x, 8.f, pe0), fmaf(v4.y, 8.f, pe1));
        X[base + 2 * q + 1] = packh2(fmaf(v4.z, 8.f, pe2), fmaf(v4.w, 8.f, pe3));
      }
    }
  } else {
    #pragma unroll
    for (int dp = 0; dp < 32; dp++) X[base + dp] = 0u;   // pad rows stay 0
  }
  __syncthreads();

  const int l15 = lane & 15;
  const int g4 = lane >> 4;               // 0..3
  uint32_t* hw = scratch + wv * 16 * HWS; // this wave's H slice [16 rows][17 u32]

  for (int l = 0; l < NL; l++) {
    const float* n1g = n1_g + l * 64;
    const float* n1b = n1_b + l * 64;
    const float* n2g = n2_g + l * 64;
    const float* n2b = n2_b + l * 64;
    const float* f1b = ff1_b + l * 64;
    const float* f2b = ff2_b + l * 64;
    const f16* w1l = w1h + l * 4096;
    const f16* w2l = w2h + l * 4096;

    // ------- avg over sequence: column-parallel partials into redbuf -------
    {
      int cp = t & 31, rg = t >> 5;
      float s0 = 0.f, s1 = 0.f;
      for (int r = rg; r < 1000; r += 32) {
        float2 v = unpackh2(X[r * XS + cp]);
        s0 += v.x;
        s1 += v.y;
      }
      redbuf[rg * 64 + 2 * cp] = s0;
      redbuf[rg * 64 + 2 * cp + 1] = s1;
    }
    __syncthreads();
    if (t < 64) {
      float s = 0.f;
      #pragma unroll
      for (int w = 0; w < 32; w++) s += redbuf[w * 64 + t];
      avgbuf[t] = s * 1e-3f;
    }
    if (t < 64) {  // attn[o] = lin_b[o] + sum_d avg[d]*lin_w[o][d] (wave0-local)
      const float* wr = lin_w + (size_t)(l * 64 + t) * 64;
      float a0 = lin_b[l * 64 + t], a1 = 0.f, a2 = 0.f, a3 = 0.f;
      #pragma unroll
      for (int d = 0; d < 64; d += 4) {
        a0 += avgbuf[d] * wr[d];
        a1 += avgbuf[d + 1] * wr[d + 1];
        a2 += avgbuf[d + 2] * wr[d + 2];
        a3 += avgbuf[d + 3] * wr[d + 3];
      }
      attnbuf[t] = (a0 + a1) + (a2 + a3);
    }
    __syncthreads();

    // ---------------- LN1 (thread t = row t; wave-local for FF) ----------------
    if (valid) {
      const float2* at2 = (const float2*)attnbuf;
      float m0 = 0.f, m1 = 0.f, q0 = 0.f, q1 = 0.f;
      for (int dp = 0; dp < 32; dp++) {
        float2 xv = unpackh2(X[base + dp]);
        float2 at = at2[dp];
        float a0 = xv.x + at.x, a1 = xv.y + at.y;
        m0 += a0;
        m1 += a1;
        q0 = fmaf(a0, a0, q0);
        q1 = fmaf(a1, a1, q1);
      }
      float mu = (m0 + m1) * (1.0f / 64.0f);
      float var = (q0 + q1) * (1.0f / 64.0f) - mu * mu;
      float rs = rsqrtf(var + 1e-5f);
      for (int dp = 0; dp < 32; dp++) {
        float2 xv = unpackh2(X[base + dp]);
        float2 at = at2[dp];
        float a0 = xv.x + at.x, a1 = xv.y + at.y;
        float y0 = fmaf((a0 - mu) * rs, n1g[2 * dp], n1b[2 * dp]);
        float y1 = fmaf((a1 - mu) * rs, n1g[2 * dp + 1], n1b[2 * dp + 1]);
        X[base + dp] = packh2(y0, y1);
      }
    }
    // no barrier: each wave's FF consumes only its own 64 rows (lanes of this
    // wave wrote them; compiler orders ds ops via lgkmcnt).

    // ---------------- FF: wave-independent, swapped MFMA ----------------
    #pragma unroll 1
    for (int rg = 0; rg < 4; rg++) {
      const int s = wv * 64 + rg * 16 + l15;   // this lane's seq-row (B-col)
      const int sb = s * XS;
      // B1 = Y^T fragments: lane holds Y[s][d=8*g4+j] (dk=0), +32 (dk=1)
      u32x4 b1q0 = {X[sb + 4 * g4], X[sb + 4 * g4 + 1],
                    X[sb + 4 * g4 + 2], X[sb + 4 * g4 + 3]};
      u32x4 b1q1 = {X[sb + 16 + 4 * g4], X[sb + 16 + 4 * g4 + 1],
                    X[sb + 16 + 4 * g4 + 2], X[sb + 16 + 4 * g4 + 3]};
      f16x8 B1k0 = __builtin_bit_cast(f16x8, b1q0);
      f16x8 B1k1 = __builtin_bit_cast(f16x8, b1q1);
      // mm2 accumulators (T^T), init bias2: acc[i] <-> o2 = 16*oot + 4*g4 + i
      f32x4 accT0 = *(const f32x4*)(f2b + 0 + 4 * g4);
      f32x4 accT1 = *(const f32x4*)(f2b + 16 + 4 * g4);
      f32x4 accT2 = *(const f32x4*)(f2b + 32 + 4 * g4);
      f32x4 accT3 = *(const f32x4*)(f2b + 48 + 4 * g4);
      #pragma unroll
      for (int hk = 0; hk < 2; hk++) {
        // mm1: H^T for h in [32*hk, 32*hk+32), two 16-o tiles
        #pragma unroll
        for (int otl = 0; otl < 2; otl++) {
          const int ot = 2 * hk + otl;
          const f16* w1p = w1l + (16 * ot + l15) * 64 + 8 * g4;
          f16x8 A0 = *(const f16x8*)(w1p);        // d = 8g4+j
          f16x8 A1 = *(const f16x8*)(w1p + 32);   // d = 32+8g4+j
          f32x4 acc = *(const f32x4*)(f1b + 16 * ot + 4 * g4);
          acc = __builtin_amdgcn_mfma_f32_16x16x32_f16(A0, B1k0, acc, 0, 0, 0);
          acc = __builtin_amdgcn_mfma_f32_16x16x32_f16(A1, B1k1, acc, 0, 0, 0);
          // lane holds H[s=l15][h=16*ot+4*g4+i]; write half-local words
          hw[l15 * HWS + 8 * otl + 2 * g4] =
              packh2(fmaxf(acc[0], 0.f), fmaxf(acc[1], 0.f));
          hw[l15 * HWS + 8 * otl + 2 * g4 + 1] =
              packh2(fmaxf(acc[2], 0.f), fmaxf(acc[3], 0.f));
        }
        // mm2 partial: B2 = H[s=l15][h-local = 8*g4+j]
        u32x4 hq = {hw[l15 * HWS + 4 * g4], hw[l15 * HWS + 4 * g4 + 1],
                    hw[l15 * HWS + 4 * g4 + 2], hw[l15 * HWS + 4 * g4 + 3]};
        f16x8 B2 = __builtin_bit_cast(f16x8, hq);
        accT0 = __builtin_amdgcn_mfma_f32_16x16x32_f16(
            *(const f16x8*)(w2l + (0 + l15) * 64 + 32 * hk + 8 * g4), B2, accT0, 0, 0, 0);
        accT1 = __builtin_amdgcn_mfma_f32_16x16x32_f16(
            *(const f16x8*)(w2l + (16 + l15) * 64 + 32 * hk + 8 * g4), B2, accT1, 0, 0, 0);
        accT2 = __builtin_amdgcn_mfma_f32_16x16x32_f16(
            *(const f16x8*)(w2l + (32 + l15) * 64 + 32 * hk + 8 * g4), B2, accT2, 0, 0, 0);
        accT3 = __builtin_amdgcn_mfma_f32_16x16x32_f16(
            *(const f16x8*)(w2l + (48 + l15) * 64 + 32 * hk + 8 * g4), B2, accT3, 0, 0, 0);
      }
      // ---- residual + in-register LN2 (lane holds 16 of row s's 64 values) ----
      float sum = 0.f, sq = 0.f;
#define RES(OO, ACC) { \
      uint32_t y0 = X[sb + 8 * OO + 2 * g4], y1 = X[sb + 8 * OO + 2 * g4 + 1]; \
      float2 f0 = unpackh2(y0), f1 = unpackh2(y1); \
      ACC[0] += f0.x; ACC[1] += f0.y; ACC[2] += f1.x; ACC[3] += f1.y; \
      sum += (ACC[0] + ACC[1]) + (ACC[2] + ACC[3]); \
      sq = fmaf(ACC[0], ACC[0], sq); sq = fmaf(ACC[1], ACC[1], sq); \
      sq = fmaf(ACC[2], ACC[2], sq); sq = fmaf(ACC[3], ACC[3], sq); }
      RES(0, accT0) RES(1, accT1) RES(2, accT2) RES(3, accT3)
#undef RES
      sum += __shfl_xor(sum, 16, 64);
      sum += __shfl_xor(sum, 32, 64);
      sq += __shfl_xor(sq, 16, 64);
      sq += __shfl_xor(sq, 32, 64);
      float mu2 = sum * (1.0f / 64.0f);
      float var2 = sq * (1.0f / 64.0f) - mu2 * mu2;
      float rs2 = rsqrtf(var2 + 1e-5f);
      const bool rv = (s < 1000);
#define WB(OO, ACC) { \
      f32x4 gg = *(const f32x4*)(n2g + 16 * OO + 4 * g4); \
      f32x4 bb = *(const f32x4*)(n2b + 16 * OO + 4 * g4); \
      float x0 = rv ? fmaf((ACC[0] - mu2) * rs2, gg[0], bb[0]) : 0.f; \
      float x1 = rv ? fmaf((ACC[1] - mu2) * rs2, gg[1], bb[1]) : 0.f; \
      float x2 = rv ? fmaf((ACC[2] - mu2) * rs2, gg[2], bb[2]) : 0.f; \
      float x3 = rv ? fmaf((ACC[3] - mu2) * rs2, gg[3], bb[3]) : 0.f; \
      X[sb + 8 * OO + 2 * g4] = packh2(x0, x1); \
      X[sb + 8 * OO + 2 * g4 + 1] = packh2(x2, x3); }
      WB(0, accT0) WB(1, accT1) WB(2, accT2) WB(3, accT3)
#undef WB
    }
    __syncthreads();   // all rows updated before next layer's avg
  }

  // ---------------- output projection [B,S,2] ----------------
  if (valid) {
    float a0 = out_b[0], a1 = out_b[1];
    for (int dp = 0; dp < 32; dp++) {
      float2 xv = unpackh2(X[base + dp]);
      a0 += xv.x * out_w[2 * dp] + xv.y * out_w[2 * dp + 1];
      a1 += xv.x * out_w[64 + 2 * dp] + xv.y * out_w[64 + 2 * dp + 1];
    }
    *(float2*)(out + (size_t)(b * 1000 + t) * 2) = make_float2(a0, a1);
  }
}

extern "C" void kernel_launch(void* const* d_in, const int* in_sizes, int n_in,
                              void* d_out, int out_size, void* d_ws, size_t ws_size,
                              hipStream_t stream) {
  const int* tokens = (const int*)d_in[0];
  const float* emb = (const float*)d_in[1];
  const float* lin_w = (const float*)d_in[2];
  const float* lin_b = (const float*)d_in[3];
  const float* ff1_w = (const float*)d_in[4];
  const float* ff1_b = (const float*)d_in[5];
  const float* ff2_w = (const float*)d_in[6];
  const float* ff2_b = (const float*)d_in[7];
  const float* n1_g = (const float*)d_in[8];
  const float* n1_b = (const float*)d_in[9];
  const float* n2_g = (const float*)d_in[10];
  const float* n2_b = (const float*)d_in[11];
  const float* out_w = (const float*)d_in[12];
  const float* out_b = (const float*)d_in[13];
  float* out = (float*)d_out;

  f16* w1h = (f16*)d_ws;                         // 32 KiB
  f16* w2h = w1h + 16384;                        // 32 KiB
  float* petab = (float*)((char*)d_ws + 65536);  // 250 KiB (1000*64 f32)
  const size_t need = 65536 + 64000 * 4;
  const bool use_pe = (ws_size >= need);
  float* pe_arg = use_pe ? petab : nullptr;

  int pack_threads = 32768 + (use_pe ? 64000 : 0);
  int pack_blocks = (pack_threads + 255) / 256;
  pack_weights_kernel<<<pack_blocks, 256, 0, stream>>>(ff1_w, ff2_w, w1h, w2h, pe_arg);
  aat_kernel<<<512, TPB, 0, stream>>>(tokens, emb, lin_w, lin_b, ff1_b, ff2_b,
                                      n1_g, n1_b, n2_g, n2_b, out_w, out_b,
                                      w1h, w2h, pe_arg, out);
}

// Round 10
// 389.236 us; speedup vs baseline: 1.1445x; 1.1445x over previous
//
#include <hip/hip_runtime.h>
#include <stdint.h>

#define TPB 1024
#define NL 4
#define XS 33      // u32 row stride (+1 pad: row & column access both conflict-free)
#define CH 128     // GEMM chunk rows
#define NCHUNK 8   // 1024 / CH

typedef _Float16 f16;
typedef _Float16 half2v __attribute__((ext_vector_type(2)));
typedef _Float16 f16x8 __attribute__((ext_vector_type(8)));
typedef float f32x4 __attribute__((ext_vector_type(4)));
typedef uint32_t u32x4 __attribute__((ext_vector_type(4)));

static __device__ __forceinline__ uint32_t packh2(float a, float b) {
  half2v h;
  h.x = (_Float16)a;
  h.y = (_Float16)b;
  return __builtin_bit_cast(uint32_t, h);
}
static __device__ __forceinline__ float2 unpackh2(uint32_t u) {
  half2v h = __builtin_bit_cast(half2v, u);
  return make_float2((float)h.x, (float)h.y);
}

// w1h/w2h: plain f16 copies of ff1_w/ff2_w in original [l][o][d] layout
// (B-fragment for MFMA = 16B contiguous in d -> one aligned dwordx4 load).
// petab[s][d] = PE(s,d) when petab != nullptr.
__global__ void pack_weights_kernel(const float* __restrict__ ff1_w,
                                    const float* __restrict__ ff2_w,
                                    f16* __restrict__ w1h,
                                    f16* __restrict__ w2h,
                                    float* __restrict__ petab) {
  int idx = blockIdx.x * blockDim.x + threadIdx.x;
  if (idx < 16384) {
    w1h[idx] = (f16)ff1_w[idx];
  } else if (idx < 32768) {
    w2h[idx - 16384] = (f16)ff2_w[idx - 16384];
  } else if (petab != nullptr && idx < 32768 + 64000) {
    int j = idx - 32768;
    int s = j >> 6, d = j & 63;
    // div_i = 10000^(-i/32), i = d>>1 ; log2(10000)/32 = 0.41524101186
    float div = exp2f(-0.4152410118609203f * (float)(d >> 1));
    float ang = (float)s * div;
    petab[j] = (d & 1) ? cosf(ang) : sinf(ang);
  }
}

// R8 structure (verified 272us, spill-free at the backend's fixed 64-VGPR
// choice) + paired-u32 LDS access in the FF epilogues. R8's 2.94e7 bank
// conflicts came from per-lane u16 scatters where lane pairs hit the SAME
// dword (write serialization). MFMA C-layout puts adjacent output columns in
// adjacent lanes (l15^1), so one shfl_xor(.,1) packs pairs into full u32
// words: even lanes write rows {0,1}, odd lanes rows {2,3} (branchless).
// R9's wave-swapped design is abandoned: its larger live set spilled 358 MB
// at the immovable 64-VGPR budget. Every phase here stays under ~60 live.
__global__ __launch_bounds__(TPB) void aat_kernel(
    const int* __restrict__ tokens, const float* __restrict__ emb,
    const float* __restrict__ lin_w, const float* __restrict__ lin_b,
    const float* __restrict__ ff1_b, const float* __restrict__ ff2_b,
    const float* __restrict__ n1_g, const float* __restrict__ n1_b,
    const float* __restrict__ n2_g, const float* __restrict__ n2_b,
    const float* __restrict__ out_w, const float* __restrict__ out_b,
    const f16* __restrict__ w1h, const f16* __restrict__ w2h,
    const float* __restrict__ petab, float* __restrict__ out) {
  __shared__ uint32_t X[1024 * XS];       // 135168 B: rows as f16 pairs
  __shared__ uint32_t Hbuf[CH * XS];      // 16896 B: H chunk / avg redbuf
  __shared__ float avgbuf[64];
  __shared__ __align__(8) float attnbuf[64];

  const int t = threadIdx.x;
  const int b = blockIdx.x;
  const int lane = t & 63;
  const bool valid = (t < 1000);
  const int base = t * XS;
  float* redbuf = (float*)Hbuf;           // [32][64] during avg phase
  const int wv = t >> 6;                  // 0..15

  // ---------------- embed * sqrt(d) + positional encoding -> X ----------------
  if (valid) {
    int tok = tokens[b * 1000 + t];
    const float4* ev = (const float4*)(emb + (size_t)tok * 64);
    if (petab != nullptr) {
      const float4* pv = (const float4*)(petab + (size_t)t * 64);
      #pragma unroll
      for (int q = 0; q < 16; q++) {
        float4 v4 = ev[q];
        float4 p4 = pv[q];
        X[base + 2 * q] = packh2(fmaf(v4.x, 8.f, p4.x), fmaf(v4.y, 8.f, p4.y));
        X[base + 2 * q + 1] = packh2(fmaf(v4.z, 8.f, p4.z), fmaf(v4.w, 8.f, p4.w));
      }
    } else {
      float fs = (float)t;
      #pragma unroll
      for (int q = 0; q < 16; q++) {
        float4 v4 = ev[q];
        float d0 = exp2f(-0.4152410118609203f * (float)((4 * q) >> 1));
        float d1 = exp2f(-0.4152410118609203f * (float)((4 * q + 2) >> 1));
        float pe0 = sinf(fs * d0), pe1 = cosf(fs * d0);
        float pe2 = sinf(fs * d1), pe3 = cosf(fs * d1);
        X[base + 2 * q] = packh2(fmaf(v4.x, 8.f, pe0), fmaf(v4.y, 8.f, pe1));
        X[base + 2 * q + 1] = packh2(fmaf(v4.z, 8.f, pe2), fmaf(v4.w, 8.f, pe3));
      }
    }
  } else {
    #pragma unroll
    for (int dp = 0; dp < 32; dp++) X[base + dp] = 0u;   // pad rows stay 0
  }
  __syncthreads();

  const int l15 = lane & 15;
  const int g4 = lane >> 4;               // 0..3
  const int nt = wv & 3;                  // this wave's output-column tile
  const int mt0 = wv >> 2;                // first row-tile (second = mt0+4)
  const int colo = nt * 16 + l15;         // this lane's output column
  const int wi = colo >> 1;               // packed word column
  const bool evenl = (l15 & 1) == 0;

  for (int l = 0; l < NL; l++) {
    const float* n1g = n1_g + l * 64;
    const float* n1b = n1_b + l * 64;
    const float* n2g = n2_g + l * 64;
    const float* n2b = n2_b + l * 64;

    // ------- avg over sequence: column-parallel partials into redbuf -------
    {
      int cp = t & 31, rg = t >> 5;
      float s0 = 0.f, s1 = 0.f;
      for (int r = rg; r < 1000; r += 32) {
        float2 v = unpackh2(X[r * XS + cp]);
        s0 += v.x;
        s1 += v.y;
      }
      redbuf[rg * 64 + 2 * cp] = s0;
      redbuf[rg * 64 + 2 * cp + 1] = s1;
    }
    __syncthreads();
    if (t < 64) {
      float s = 0.f;
      #pragma unroll
      for (int w = 0; w < 32; w++) s += redbuf[w * 64 + t];
      avgbuf[t] = s * 1e-3f;
    }
    __syncthreads();
    if (t < 64) {  // attn[o] = lin_b[o] + sum_d avg[d]*lin_w[o][d]
      const float* wr = lin_w + (size_t)(l * 64 + t) * 64;
      float a0 = lin_b[l * 64 + t], a1 = 0.f, a2 = 0.f, a3 = 0.f;
      #pragma unroll
      for (int d = 0; d < 64; d += 4) {
        a0 += avgbuf[d] * wr[d];
        a1 += avgbuf[d + 1] * wr[d + 1];
        a2 += avgbuf[d + 2] * wr[d + 2];
        a3 += avgbuf[d + 3] * wr[d + 3];
      }
      attnbuf[t] = (a0 + a1) + (a2 + a3);
    }
    __syncthreads();

    // ---------------- LN1 (thread-per-row): Y overwrites X ----------------
    if (valid) {
      const float2* at2 = (const float2*)attnbuf;
      float m0 = 0.f, m1 = 0.f, q0 = 0.f, q1 = 0.f;
      for (int dp = 0; dp < 32; dp++) {
        float2 xv = unpackh2(X[base + dp]);
        float2 at = at2[dp];
        float a0 = xv.x + at.x, a1 = xv.y + at.y;
        m0 += a0;
        m1 += a1;
        q0 = fmaf(a0, a0, q0);
        q1 = fmaf(a1, a1, q1);
      }
      float mu = (m0 + m1) * (1.0f / 64.0f);
      float var = (q0 + q1) * (1.0f / 64.0f) - mu * mu;
      float rs = rsqrtf(var + 1e-5f);
      for (int dp = 0; dp < 32; dp++) {
        float2 xv = unpackh2(X[base + dp]);
        float2 at = at2[dp];
        float a0 = xv.x + at.x, a1 = xv.y + at.y;
        float y0 = fmaf((a0 - mu) * rs, n1g[2 * dp], n1b[2 * dp]);
        float y1 = fmaf((a1 - mu) * rs, n1g[2 * dp + 1], n1b[2 * dp + 1]);
        X[base + dp] = packh2(y0, y1);
      }
    }
    __syncthreads();

    // ---------------- FF via MFMA, chunked ----------------
    const f16* w1p = w1h + l * 4096 + colo * 64 + g4 * 8;
    f16x8 B1k0 = *(const f16x8*)(w1p);
    f16x8 B1k1 = *(const f16x8*)(w1p + 32);
    const f16* w2p = w2h + l * 4096 + colo * 64 + g4 * 8;
    f16x8 B2k0 = *(const f16x8*)(w2p);
    f16x8 B2k1 = *(const f16x8*)(w2p + 32);
    const float bias1 = ff1_b[l * 64 + colo];
    const float bias2 = ff2_b[l * 64 + colo];

    for (int c = 0; c < NCHUNK; c++) {
      // --- mm1 chunk: H = relu(Y @ W1^T + b1) -> Hbuf, paired u32 writes ---
      #pragma unroll
      for (int jj = 0; jj < 2; jj++) {
        const int mt = mt0 + 4 * jj;
        const int rowA = c * CH + mt * 16 + l15;
        f32x4 acc = {bias1, bias1, bias1, bias1};
        {
          int p = rowA * XS + g4 * 4;
          u32x4 aw = {X[p], X[p + 1], X[p + 2], X[p + 3]};
          acc = __builtin_amdgcn_mfma_f32_16x16x32_f16(
              __builtin_bit_cast(f16x8, aw), B1k0, acc, 0, 0, 0);
        }
        {
          int p = rowA * XS + 16 + g4 * 4;
          u32x4 aw = {X[p], X[p + 1], X[p + 2], X[p + 3]};
          acc = __builtin_amdgcn_mfma_f32_16x16x32_f16(
              __builtin_bit_cast(f16x8, aw), B1k1, acc, 0, 0, 0);
        }
        // lane holds H[rows rb+0..3][col colo]; partner lane (l15^1) = col^1
        float h0 = fmaxf(acc[0], 0.f), h1 = fmaxf(acc[1], 0.f);
        float h2 = fmaxf(acc[2], 0.f), h3 = fmaxf(acc[3], 0.f);
        float p0 = __shfl_xor(h0, 1, 64), p1 = __shfl_xor(h1, 1, 64);
        float p2 = __shfl_xor(h2, 1, 64), p3 = __shfl_xor(h3, 1, 64);
        const int rb = mt * 16 + g4 * 4;          // chunk-local row base
        uint32_t wv0 = evenl ? packh2(h0, p0) : packh2(p2, h2);
        uint32_t wv1 = evenl ? packh2(h1, p1) : packh2(p3, h3);
        int r0 = evenl ? rb : rb + 2;
        Hbuf[r0 * XS + wi] = wv0;
        Hbuf[(r0 + 1) * XS + wi] = wv1;
      }
      __syncthreads();
      // --- mm2 chunk: T = H @ W2^T + b2 + Y -> X (in place), paired u32 ---
      #pragma unroll
      for (int jj = 0; jj < 2; jj++) {
        const int mt = mt0 + 4 * jj;
        const int rbg = c * CH + mt * 16 + g4 * 4;   // global row base
        // residual paired read: this lane reads rows rbg+iA, rbg+iA+1
        const int iA = evenl ? 0 : 2;
        uint32_t yA = X[(rbg + iA) * XS + wi];
        uint32_t yB = X[(rbg + iA + 1) * XS + wi];
        uint32_t pA = __shfl_xor(yA, 1, 64);
        uint32_t pB = __shfl_xor(yB, 1, 64);
        uint32_t w0 = evenl ? yA : pA;   // row rbg+0 word
        uint32_t w1w = evenl ? yB : pB;  // row rbg+1
        uint32_t w2w = evenl ? pA : yA;  // row rbg+2
        uint32_t w3 = evenl ? pB : yB;   // row rbg+3
        float res0 = evenl ? unpackh2(w0).x : unpackh2(w0).y;
        float res1 = evenl ? unpackh2(w1w).x : unpackh2(w1w).y;
        float res2 = evenl ? unpackh2(w2w).x : unpackh2(w2w).y;
        float res3 = evenl ? unpackh2(w3).x : unpackh2(w3).y;
        f32x4 acc = {bias2 + res0, bias2 + res1, bias2 + res2, bias2 + res3};
        const int rowH = mt * 16 + l15;
        {
          int p = rowH * XS + g4 * 4;
          u32x4 aw = {Hbuf[p], Hbuf[p + 1], Hbuf[p + 2], Hbuf[p + 3]};
          acc = __builtin_amdgcn_mfma_f32_16x16x32_f16(
              __builtin_bit_cast(f16x8, aw), B2k0, acc, 0, 0, 0);
        }
        {
          int p = rowH * XS + 16 + g4 * 4;
          u32x4 aw = {Hbuf[p], Hbuf[p + 1], Hbuf[p + 2], Hbuf[p + 3]};
          acc = __builtin_amdgcn_mfma_f32_16x16x32_f16(
              __builtin_bit_cast(f16x8, aw), B2k1, acc, 0, 0, 0);
        }
        // paired T write (same pattern as H write)
        float q0 = __shfl_xor(acc[0], 1, 64), q1 = __shfl_xor(acc[1], 1, 64);
        float q2 = __shfl_xor(acc[2], 1, 64), q3 = __shfl_xor(acc[3], 1, 64);
        uint32_t tv0 = evenl ? packh2(acc[0], q0) : packh2(q2, acc[2]);
        uint32_t tv1 = evenl ? packh2(acc[1], q1) : packh2(q3, acc[3]);
        int ro = evenl ? rbg : rbg + 2;
        X[ro * XS + wi] = tv0;
        X[(ro + 1) * XS + wi] = tv1;
      }
      __syncthreads();
    }

    // ---------------- LN2 (thread-per-row) over T in X; pads re-zeroed ----------------
    if (valid) {
      float m0 = 0.f, m1 = 0.f, q0 = 0.f, q1 = 0.f;
      for (int dp = 0; dp < 32; dp++) {
        float2 tv = unpackh2(X[base + dp]);
        m0 += tv.x;
        m1 += tv.y;
        q0 = fmaf(tv.x, tv.x, q0);
        q1 = fmaf(tv.y, tv.y, q1);
      }
      float mu2 = (m0 + m1) * (1.0f / 64.0f);
      float var2 = (q0 + q1) * (1.0f / 64.0f) - mu2 * mu2;
      float rs2 = rsqrtf(var2 + 1e-5f);
      for (int dp = 0; dp < 32; dp++) {
        float2 tv = unpackh2(X[base + dp]);
        float x0v = fmaf((tv.x - mu2) * rs2, n2g[2 * dp], n2b[2 * dp]);
        float x1v = fmaf((tv.y - mu2) * rs2, n2g[2 * dp + 1], n2b[2 * dp + 1]);
        X[base + dp] = packh2(x0v, x1v);
      }
    } else {
      #pragma unroll
      for (int dp = 0; dp < 32; dp++) X[base + dp] = 0u;  // mm2 wrote junk to pads
    }
    __syncthreads();
  }

  // ---------------- output projection [B,S,2] ----------------
  if (valid) {
    float a0 = out_b[0], a1 = out_b[1];
    for (int dp = 0; dp < 32; dp++) {
      float2 xv = unpackh2(X[base + dp]);
      a0 += xv.x * out_w[2 * dp] + xv.y * out_w[2 * dp + 1];
      a1 += xv.x * out_w[64 + 2 * dp] + xv.y * out_w[64 + 2 * dp + 1];
    }
    *(float2*)(out + (size_t)(b * 1000 + t) * 2) = make_float2(a0, a1);
  }
}

extern "C" void kernel_launch(void* const* d_in, const int* in_sizes, int n_in,
                              void* d_out, int out_size, void* d_ws, size_t ws_size,
                              hipStream_t stream) {
  const int* tokens = (const int*)d_in[0];
  const float* emb = (const float*)d_in[1];
  const float* lin_w = (const float*)d_in[2];
  const float* lin_b = (const float*)d_in[3];
  const float* ff1_w = (const float*)d_in[4];
  const float* ff1_b = (const float*)d_in[5];
  const float* ff2_w = (const float*)d_in[6];
  const float* ff2_b = (const float*)d_in[7];
  const float* n1_g = (const float*)d_in[8];
  const float* n1_b = (const float*)d_in[9];
  const float* n2_g = (const float*)d_in[10];
  const float* n2_b = (const float*)d_in[11];
  const float* out_w = (const float*)d_in[12];
  const float* out_b = (const float*)d_in[13];
  float* out = (float*)d_out;

  f16* w1h = (f16*)d_ws;                         // 32 KiB
  f16* w2h = w1h + 16384;                        // 32 KiB
  float* petab = (float*)((char*)d_ws + 65536);  // 250 KiB (1000*64 f32)
  const size_t need = 65536 + 64000 * 4;
  const bool use_pe = (ws_size >= need);
  float* pe_arg = use_pe ? petab : nullptr;

  int pack_threads = 32768 + (use_pe ? 64000 : 0);
  int pack_blocks = (pack_threads + 255) / 256;
  pack_weights_kernel<<<pack_blocks, 256, 0, stream>>>(ff1_w, ff2_w, w1h, w2h, pe_arg);
  aat_kernel<<<512, TPB, 0, stream>>>(tokens, emb, lin_w, lin_b, ff1_b, ff2_b,
                                      n1_g, n1_b, n2_g, n2_b, out_w, out_b,
                                      w1h, w2h, pe_arg, out);
}